// Round 6
// baseline (47.255 us; speedup 1.0000x reference)
//
#include <hip/hip_runtime.h>
#include <hip/hip_bf16.h>

typedef float f32x4 __attribute__((ext_vector_type(4)));
typedef short bf16x8 __attribute__((ext_vector_type(8)));

#define MFMA16 __builtin_amdgcn_mfma_f32_16x16x32_bf16

static constexpr int KDIM = 1700;
static constexpr int NKT  = 54;         // k-tiles of 32 (tile 53 ragged: 4 valid)
static constexpr float BETA = 0.9f;
static constexpr float THRESH = 1.0f;

// fp32 -> bf16 hi + bf16 lo (residual), via HW cvt
__device__ __forceinline__ void split_bf(float f, short& hi, short& lo) {
    __hip_bfloat16 h = __float2bfloat16(f);
    float r = f - __bfloat162float(h);          // exact in fp32
    __hip_bfloat16 l = __float2bfloat16(r);
    hi = (short)__builtin_bit_cast(unsigned short, h);
    lo = (short)__builtin_bit_cast(unsigned short, l);
}

__device__ __forceinline__ void split8(f32x4 a, f32x4 b, bf16x8& hi, bf16x8& lo) {
    #pragma unroll
    for (int i = 0; i < 4; ++i) { short h, l; split_bf(a[i], h, l); hi[i] = h; lo[i] = l; }
    #pragma unroll
    for (int i = 0; i < 4; ++i) { short h, l; split_bf(b[i], h, l); hi[4 + i] = h; lo[4 + i] = l; }
}

// W1 [64][1700] f32 -> two bf16 planes in MFMA-B-fragment order with a
// K-PERMUTATION chosen so the matching x loads are line-contiguous:
// reg i of lane (l15,g4) holds logical k = kt*32 + (i>>2)*16 + g4*4 + (i&3).
// (Dot products are K-order invariant; x fragments use the same permutation.)
__global__ void w1_relayout(const float* __restrict__ W1,
                            short* __restrict__ WTh, short* __restrict__ WTl) {
    const int g    = blockIdx.x * 256 + threadIdx.x;   // 0 .. 54*256-1
    const int kt   = g >> 8;
    const int nt   = (g >> 6) & 3;
    const int lane = g & 63;
    const int n    = nt * 16 + (lane & 15);
    const int g4   = lane >> 4;
    bf16x8 vh, vl;
    #pragma unroll
    for (int i = 0; i < 8; ++i) {
        const int k = kt * 32 + (i >> 2) * 16 + g4 * 4 + (i & 3);
        const float v = (k < KDIM) ? W1[n * KDIM + k] : 0.f;
        short h, l; split_bf(v, h, l);
        vh[i] = h; vl[i] = l;
    }
    *(bf16x8*)(WTh + (size_t)g * 8) = vh;
    *(bf16x8*)(WTl + (size_t)g * 8) = vl;
}

// ---------------- kernel A: cur1 = x @ W1^T + b1 (split-bf16 emulated fp32) --
// Block = 512 thr = 8 waves, 64 rows/block, K split 8 ways across waves
// (waves 0-5: 7 tiles, 6-7: 6 tiles). Barrier-free main loop; explicit
// 1-tile register double-buffer for both W and x hides load latency.
__global__ __launch_bounds__(512, 2) void gemm1(
    const float* __restrict__ x,
    const short* __restrict__ WTh, const short* __restrict__ WTl,
    const float* __restrict__ b1, float* __restrict__ cur1)
{
    __shared__ float red[8][64][68];            // 139 KB (1 block/CU)
    const int tid = threadIdx.x;
    const int wid = tid >> 6;
    const int lane = tid & 63;
    const int l15 = lane & 15;
    const int g4  = lane >> 4;
    const int rowBase = blockIdx.x * 64;

    const int t0 = (wid < 6) ? wid * 7 : 42 + (wid - 6) * 6;
    const int t1 = t0 + ((wid < 6) ? 7 : 6);

    const float* xbase = x + (size_t)(rowBase + l15) * KDIM;

    // x fragment loads: with the K-perm, the 4 g4-lanes of a row read one
    // contiguous 64B line per instruction.
    auto loadx = [&](int tile, f32x4* X) {
        if (tile < 53) {
            #pragma unroll
            for (int rt = 0; rt < 4; ++rt) {
                const float* p = xbase + (size_t)rt * 16 * KDIM + tile * 32 + g4 * 4;
                X[2 * rt]     = *(const f32x4*)p;
                X[2 * rt + 1] = *(const f32x4*)(p + 16);
            }
        } else {                                // k 1696..1699 valid only
            #pragma unroll
            for (int rt = 0; rt < 4; ++rt) {
                X[2 * rt] = (f32x4){0, 0, 0, 0};
                X[2 * rt + 1] = (f32x4){0, 0, 0, 0};
                if (g4 == 0)                    // perm: g4==0 holds k 1696..1699
                    X[2 * rt] = *(const f32x4*)(xbase + (size_t)rt * 16 * KDIM + 53 * 32);
            }
        }
    };
    // W fragment loads: contiguous 1KB wave loads (hi, lo planes)
    auto loadW = [&](int t, bf16x8* Wf) {
        const short* wb = WTh + (size_t)t * 2048 + lane * 8;
        const short* wl = WTl + (size_t)t * 2048 + lane * 8;
        #pragma unroll
        for (int nt = 0; nt < 4; ++nt) {
            Wf[nt]     = *(const bf16x8*)(wb + nt * 512);
            Wf[4 + nt] = *(const bf16x8*)(wl + nt * 512);
        }
    };

    f32x4 xc[8], xn[8];
    bf16x8 Wc[8], Wn[8];
    loadx(t0, xc);
    loadW(t0, Wc);

    f32x4 acc[4][4] = {};
    for (int t = t0; t < t1; ++t) {
        const bool more = (t + 1 < t1);
        if (more) { loadW(t + 1, Wn); loadx(t + 1, xn); }
        #pragma unroll
        for (int rt = 0; rt < 4; ++rt) {
            bf16x8 ah, al;
            split8(xc[2 * rt], xc[2 * rt + 1], ah, al);
            #pragma unroll
            for (int nt = 0; nt < 4; ++nt) {
                acc[rt][nt] = MFMA16(ah, Wc[nt], acc[rt][nt], 0, 0, 0);
                acc[rt][nt] = MFMA16(al, Wc[nt], acc[rt][nt], 0, 0, 0);
                acc[rt][nt] = MFMA16(ah, Wc[4 + nt], acc[rt][nt], 0, 0, 0);
            }
        }
        if (more) {
            #pragma unroll
            for (int i = 0; i < 8; ++i) { Wc[i] = Wn[i]; xc[i] = xn[i]; }
        }
    }

    // partials -> LDS (C-layout: row = rt*16 + g4*4 + j, col = nt*16 + l15)
    #pragma unroll
    for (int rt = 0; rt < 4; ++rt)
        #pragma unroll
        for (int nt = 0; nt < 4; ++nt)
            #pragma unroll
            for (int j = 0; j < 4; ++j)
                red[wid][rt * 16 + g4 * 4 + j][nt * 16 + l15] = acc[rt][nt][j];
    __syncthreads();

    // reduce 8 k-partials + b1; 512 tasks = 64 rows x 8 segs, coalesced stores
    {
        const int row = tid >> 3;
        const int seg = tid & 7;
        f32x4 s0 = *(const f32x4*)(b1 + seg * 8);
        f32x4 s1 = *(const f32x4*)(b1 + seg * 8 + 4);
        #pragma unroll
        for (int p = 0; p < 8; ++p) {
            s0 += *(const f32x4*)&red[p][row][seg * 8];
            s1 += *(const f32x4*)&red[p][row][seg * 8 + 4];
        }
        float* cp = cur1 + (size_t)(rowBase + row) * 64 + seg * 8;
        *(f32x4*)cp = s0;
        *(f32x4*)(cp + 4) = s1;
    }
}

// ---------------- kernel B: 20-step LIF recurrence + final projection --------
__global__ __launch_bounds__(256, 2) void recur(
    const float* __restrict__ cur1, const float* __restrict__ W2,
    const float* __restrict__ b2, const float* __restrict__ W3,
    const float* __restrict__ b3, const int* __restrict__ nsp,
    float* __restrict__ out)
{
    const int tid = threadIdx.x;
    const int wid = tid >> 6;
    const int lane = tid & 63;
    const int l15 = lane & 15;
    const int g4  = lane >> 4;
    const int kg  = g4 * 8;
    const int row = blockIdx.x * 64 + wid * 16 + l15;

    float c1[2][8];
    #pragma unroll
    for (int kt = 0; kt < 2; ++kt) {
        f32x4 u0 = *(const f32x4*)(cur1 + (size_t)row * 64 + kt * 32 + kg);
        f32x4 u1 = *(const f32x4*)(cur1 + (size_t)row * 64 + kt * 32 + kg + 4);
        #pragma unroll
        for (int i = 0; i < 4; ++i) { c1[kt][i] = u0[i]; c1[kt][4 + i] = u1[i]; }
    }

    bf16x8 W2hf[2][2], W2lf[2][2];
    #pragma unroll
    for (int rt = 0; rt < 2; ++rt)
        #pragma unroll
        for (int kt = 0; kt < 2; ++kt) {
            const float* wp = W2 + (rt * 16 + l15) * 64 + kt * 32 + kg;
            split8(*(const f32x4*)wp, *(const f32x4*)(wp + 4), W2hf[rt][kt], W2lf[rt][kt]);
        }

    float b2v[2][4], w3a[2][4], w3b[2][4];
    #pragma unroll
    for (int nt = 0; nt < 2; ++nt)
        #pragma unroll
        for (int j = 0; j < 4; ++j) {
            const int o = nt * 16 + g4 * 4 + j;
            b2v[nt][j] = b2[o];
            w3a[nt][j] = W3[o];
            w3b[nt][j] = W3[32 + o];
        }

    float m1[2][8] = {};
    float m2[2][4] = {};
    const int ns = nsp[0];
    for (int s = 0; s < ns; ++s) {
        bf16x8 mh[2], ml[2];
        #pragma unroll
        for (int kt = 0; kt < 2; ++kt)
            #pragma unroll
            for (int i = 0; i < 8; ++i) {
                float m = m1[kt][i];
                float rr = (m > THRESH) ? THRESH : 0.f;
                m = __builtin_fmaf(BETA, m, c1[kt][i] - rr);
                m1[kt][i] = m;
                short h, l; split_bf(m, h, l);
                mh[kt][i] = h; ml[kt][i] = l;
            }
        f32x4 a2[2][2] = {};
        #pragma unroll
        for (int rt = 0; rt < 2; ++rt)
            #pragma unroll
            for (int kt = 0; kt < 2; ++kt) {
                a2[rt][kt] = MFMA16(W2hf[rt][kt], mh[kt], a2[rt][kt], 0, 0, 0);
                a2[rt][kt] = MFMA16(W2lf[rt][kt], mh[kt], a2[rt][kt], 0, 0, 0);
                a2[rt][kt] = MFMA16(W2hf[rt][kt], ml[kt], a2[rt][kt], 0, 0, 0);
            }
        #pragma unroll
        for (int nt = 0; nt < 2; ++nt) {
            f32x4 c2 = a2[nt][0] + a2[nt][1];
            #pragma unroll
            for (int j = 0; j < 4; ++j) {
                float m = m2[nt][j];
                float rr = (m > THRESH) ? THRESH : 0.f;
                m2[nt][j] = __builtin_fmaf(BETA, m, c2[j] + b2v[nt][j] - rr);
            }
        }
    }

    float p0 = 0.f, p1 = 0.f;
    #pragma unroll
    for (int nt = 0; nt < 2; ++nt)
        #pragma unroll
        for (int j = 0; j < 4; ++j) {
            p0 = __builtin_fmaf(m2[nt][j], w3a[nt][j], p0);
            p1 = __builtin_fmaf(m2[nt][j], w3b[nt][j], p1);
        }
    p0 += __shfl_xor(p0, 16); p0 += __shfl_xor(p0, 32);
    p1 += __shfl_xor(p1, 16); p1 += __shfl_xor(p1, 32);
    if (lane < 16) {
        out[(size_t)row * 2 + 0] = p0 + b3[0];
        out[(size_t)row * 2 + 1] = p1 + b3[1];
    }
}

extern "C" void kernel_launch(void* const* d_in, const int* in_sizes, int n_in,
                              void* d_out, int out_size, void* d_ws, size_t ws_size,
                              hipStream_t stream) {
    const float* x  = (const float*)d_in[0];
    const float* W1 = (const float*)d_in[1];
    const float* b1 = (const float*)d_in[2];
    const float* W2 = (const float*)d_in[3];
    const float* b2 = (const float*)d_in[4];
    const float* W3 = (const float*)d_in[5];
    const float* b3 = (const float*)d_in[6];
    const int*   ns = (const int*)d_in[7];
    float* o = (float*)d_out;

    const int B = in_sizes[0] / KDIM;              // 16384
    float* cur1 = (float*)d_ws;                    // [B][64] f32 = 4 MB
    short* WTh  = (short*)((char*)d_ws + (size_t)B * 64 * 4);
    short* WTl  = WTh + (size_t)NKT * 2048;        // each plane 54*2048 shorts

    w1_relayout<<<NKT, 256, 0, stream>>>(W1, WTh, WTl);
    gemm1<<<B / 64, 512, 0, stream>>>(x, WTh, WTl, b1, cur1);
    recur<<<B / 64, 256, 0, stream>>>(cur1, W2, b2, W3, b3, ns, o);
}